// Round 2
// baseline (1962.899 us; speedup 1.0000x reference)
//
#include <hip/hip_runtime.h>
#include <stdint.h>

static constexpr int B = 8, C = 21, H = 512, W = 512;
static constexpr int HW = H * W;          // 262144
static constexpr int N = B * HW;          // 2097152 pixels

// ---------------------------------------------------------------------------
// Pass 0: compress labels to uint8 (packed 4/word) so per-class re-reads are
// L2/L3-resident (2 MB instead of 8/16 MB). Handles int32 or int64 source.
// ---------------------------------------------------------------------------
__global__ void labels8_i32_kernel(const int4* __restrict__ tgt, unsigned* __restrict__ lab) {
    int i = blockIdx.x * blockDim.x + threadIdx.x;   // group of 4 labels
    if (i >= N / 4) return;
    int4 a = tgt[i];
    unsigned v = ((unsigned)a.x & 255u) | (((unsigned)a.y & 255u) << 8) |
                 (((unsigned)a.z & 255u) << 16) | (((unsigned)a.w & 255u) << 24);
    lab[i] = v;
}

__global__ void labels8_i64_kernel(const long long* __restrict__ tgt, unsigned* __restrict__ lab) {
    int i = blockIdx.x * blockDim.x + threadIdx.x;   // group of 4 labels
    if (i >= N / 4) return;
    unsigned v = 0;
#pragma unroll
    for (int j = 0; j < 4; ++j)
        v |= ((unsigned)tgt[4 * i + j] & 255u) << (8 * j);
    lab[i] = v;
}

// ---------------------------------------------------------------------------
// Pass 1: per-(class,bucket) histogram of (total count, gt count) packed in
// one u64: low 32 = n, high 32 = gt. One atomic per pixel-class pair.
// Bucketing: q = floor(e * nb), e in [0,1]; mul by pow2 is exact in fp32.
// ---------------------------------------------------------------------------
__global__ void hist_kernel(const float4* __restrict__ pred,
                            const unsigned* __restrict__ lab4,
                            unsigned long long* __restrict__ hist,
                            int nb, float nbf) {
    int bc = blockIdx.y;                  // plane index: b*C + c
    int b = bc / C, c = bc % C;
    int t4 = blockIdx.x * blockDim.x + threadIdx.x;   // float4 index in plane
    if (t4 >= HW / 4) return;
    float4 p = pred[(size_t)bc * (HW / 4) + t4];
    unsigned lv = lab4[(size_t)b * (HW / 4) + t4];
    unsigned long long* h = hist + (size_t)c * nb;
    float pe[4] = {p.x, p.y, p.z, p.w};
#pragma unroll
    for (int j = 0; j < 4; ++j) {
        int lj = (lv >> (8 * j)) & 255;
        int ismatch = (lj == c) ? 1 : 0;
        float e = fabsf((float)ismatch - pe[j]);
        int q = (int)(e * nbf);
        q = q < nb ? q : nb - 1;
        q = q < 0 ? 0 : q;
        atomicAdd(&h[q], 1ULL | ((unsigned long long)ismatch << 32));
    }
}

// ---------------------------------------------------------------------------
// Pass 2: per class (one block), scan buckets in DESCENDING error order.
// Running (k, cg) = cumulative (total, gt) counts; a tied bucket's total
// contribution telescopes to e_rep * (J(k+n,cg+g) - J(k,cg)),
// J(k,cg) = 1 - (G-cg)/(G+k-cg).  Tie order inside a bucket is irrelevant
// (adjacent-swap invariance), and quantization error <= (half bucket) * 1.
// ---------------------------------------------------------------------------
__global__ void scan_kernel(const unsigned long long* __restrict__ hist,
                            int nb,
                            double* __restrict__ loss_out,
                            unsigned long long* __restrict__ g_out) {
    int c = blockIdx.x;
    const unsigned long long* h = hist + (size_t)c * nb;
    int tid = threadIdx.x;
    int per = nb / 256;

    unsigned long long nsum = 0, gsum = 0;
    for (int j = 0; j < per; ++j) {
        int q = nb - 1 - (tid * per + j);
        unsigned long long v = h[q];
        nsum += (v & 0xffffffffULL);
        gsum += (v >> 32);
    }
    __shared__ unsigned long long sn[256], sg[256];
    __shared__ unsigned long long exn[257], exg[257];
    sn[tid] = nsum; sg[tid] = gsum;
    __syncthreads();
    if (tid == 0) {
        unsigned long long an = 0, ag = 0;
        for (int i = 0; i < 256; ++i) { exn[i] = an; exg[i] = ag; an += sn[i]; ag += sg[i]; }
        exn[256] = an; exg[256] = ag;
    }
    __syncthreads();

    unsigned long long G = exg[256];
    double acc = 0.0;
    if (G > 0) {
        double Gd = (double)G;
        double k  = (double)exn[tid];
        double cg = (double)exg[tid];
        double jprev = 1.0 - (Gd - cg) / (Gd + k - cg);   // J at thread's prefix
        double inv_nb = 1.0 / (double)nb;
        for (int j = 0; j < per; ++j) {
            int q = nb - 1 - (tid * per + j);
            unsigned long long v = h[q];
            unsigned long long n = v & 0xffffffffULL;
            if (n) {
                unsigned long long g = v >> 32;
                k += (double)n; cg += (double)g;
                double jnew = 1.0 - (Gd - cg) / (Gd + k - cg);
                acc += (((double)q + 0.5) * inv_nb) * (jnew - jprev);
                jprev = jnew;
            }
        }
    }
    __shared__ double red[256];
    red[tid] = acc;
    __syncthreads();
    for (int s = 128; s > 0; s >>= 1) {
        if (tid < s) red[tid] += red[tid + s];
        __syncthreads();
    }
    if (tid == 0) { loss_out[c] = red[0]; g_out[c] = G; }
}

// ---------------------------------------------------------------------------
// Pass 3: mean over present classes.
// ---------------------------------------------------------------------------
__global__ void finalize_kernel(const double* __restrict__ loss,
                                const unsigned long long* __restrict__ g,
                                float* __restrict__ out) {
    if (blockIdx.x == 0 && threadIdx.x == 0) {
        double s = 0.0; int np = 0;
        for (int c = 0; c < C; ++c) if (g[c] > 0) { s += loss[c]; ++np; }
        out[0] = (float)(s / (double)(np > 0 ? np : 1));
    }
}

extern "C" void kernel_launch(void* const* d_in, const int* in_sizes, int n_in,
                              void* d_out, int out_size, void* d_ws, size_t ws_size,
                              hipStream_t stream) {
    const float* pred = (const float*)d_in[0];
    float* out = (float*)d_out;

    // Pick bucket count that fits the workspace (power of two; 2^16 preferred:
    // quantization error <= 2^-17, far below the 1.77e-2 threshold).
    int nb = 1 << 16;
    while (nb > 1024) {
        size_t need = (size_t)N + (size_t)C * nb * 8 + 1024;
        if (need <= ws_size) break;
        nb >>= 1;
    }

    char* ws = (char*)d_ws;
    unsigned* lab = (unsigned*)ws;                                  // N bytes
    unsigned long long* hist = (unsigned long long*)(ws + N);       // C*nb*8
    double* loss = (double*)(ws + N + (size_t)C * nb * 8);          // C*8
    unsigned long long* g = (unsigned long long*)(loss + C);        // C*8

    hipMemsetAsync(hist, 0, (size_t)C * nb * 8, stream);

    // Label dtype: int64 in the reference; harness may marshal as int32.
    // If in_sizes[1] reports N elements, treat the buffer per 4-byte words
    // only when it was actually narrowed; detect via element count.
    if (in_sizes[1] == N) {
        // Could be int32 (narrowed) — reference says integer -> const int*.
        labels8_i32_kernel<<<dim3((N / 4 + 255) / 256), dim3(256), 0, stream>>>(
            (const int4*)d_in[1], lab);
    } else {
        // 64-bit words kept (element count == N but 8B each would report N; be
        // safe: any other count -> read as int64 with stride 1).
        labels8_i64_kernel<<<dim3((N / 4 + 255) / 256), dim3(256), 0, stream>>>(
            (const long long*)d_in[1], lab);
    }

    hist_kernel<<<dim3(HW / 4 / 256, B * C), dim3(256), 0, stream>>>(
        (const float4*)pred, lab, hist, nb, (float)nb);
    scan_kernel<<<dim3(C), dim3(256), 0, stream>>>(hist, nb, loss, g);
    finalize_kernel<<<1, 64, 0, stream>>>(loss, g, out);
}

// Round 3
// 64.427 us; speedup vs baseline: 30.4672x; 30.4672x over previous
//
#include <hip/hip_runtime.h>
#include <stdint.h>

static constexpr int B = 8, C = 21, H = 512, W = 512;
static constexpr int HW = H * W;          // 262144
static constexpr int N = B * HW;          // 2097152 pixels
static constexpr int CHUNKS = 8;          // chunks per (b,c) plane
static constexpr int PPC = HW / CHUNKS;   // 32768 pixels per workgroup (< 2^16: u16-safe)
static constexpr int ITER = PPC / 4 / 256;// 32 float4 loads per thread
static constexpr int NPART = B * CHUNKS;  // 64 partial hists per class
static constexpr int NBMAX = 4096;

// ---------------------------------------------------------------------------
// Pass 0: compress labels to uint8 (packed 4/word): per-class re-reads become
// 2 MB, fully L3-resident.
// ---------------------------------------------------------------------------
__global__ void labels8_i32_kernel(const int4* __restrict__ tgt, unsigned* __restrict__ lab) {
    int i = blockIdx.x * blockDim.x + threadIdx.x;
    if (i >= N / 4) return;
    int4 a = tgt[i];
    lab[i] = ((unsigned)a.x & 255u) | (((unsigned)a.y & 255u) << 8) |
             (((unsigned)a.z & 255u) << 16) | (((unsigned)a.w & 255u) << 24);
}

__global__ void labels8_i64_kernel(const long long* __restrict__ tgt, unsigned* __restrict__ lab) {
    int i = blockIdx.x * blockDim.x + threadIdx.x;
    if (i >= N / 4) return;
    unsigned v = 0;
#pragma unroll
    for (int j = 0; j < 4; ++j)
        v |= ((unsigned)tgt[4 * i + j] & 255u) << (8 * j);
    lab[i] = v;
}

// ---------------------------------------------------------------------------
// Pass 1: LDS-privatized per-(class,bucket) histogram. Packed u32: count in
// low 16, gt-count in high 16 (chunk = 32768 pixels -> no overflow). Flush is
// plain coalesced stores to a per-workgroup partial slab -> ZERO global
// atomics (the round-2 kernel's 1.4 GB atomic-fabric storm).
// ---------------------------------------------------------------------------
__global__ __launch_bounds__(256) void hist_kernel(const float4* __restrict__ pred,
                                                   const unsigned* __restrict__ lab4,
                                                   unsigned* __restrict__ part,
                                                   int nb, float nbf) {
    int chunk = blockIdx.x;               // 0..CHUNKS-1
    int bc = blockIdx.y;                  // b*C + c
    int b = bc / C, c = bc % C;
    int tid = threadIdx.x;

    __shared__ unsigned hcnt[NBMAX];
    for (int j = tid; j < nb; j += 256) hcnt[j] = 0;
    __syncthreads();

    const float4* pp = pred + (size_t)bc * (HW / 4) + (size_t)chunk * (PPC / 4);
    const unsigned* lp = lab4 + (size_t)b * (HW / 4) + (size_t)chunk * (PPC / 4);
    unsigned cu = (unsigned)c;
#pragma unroll 4
    for (int i = 0; i < ITER; ++i) {
        int idx = i * 256 + tid;
        float4 p = pp[idx];
        unsigned lv = lp[idx];
        float pe[4] = {p.x, p.y, p.z, p.w};
#pragma unroll
        for (int j = 0; j < 4; ++j) {
            unsigned ismatch = (((lv >> (8 * j)) & 255u) == cu) ? 1u : 0u;
            float e = fabsf((float)ismatch - pe[j]);
            int q = (int)(e * nbf);
            q = q > nb - 1 ? nb - 1 : (q < 0 ? 0 : q);
            atomicAdd(&hcnt[q], 1u | (ismatch << 16));
        }
    }
    __syncthreads();

    unsigned* dst = part + ((size_t)c * NPART + (size_t)(b * CHUNKS + chunk)) * nb;
    for (int j = tid; j < nb; j += 256) dst[j] = hcnt[j];   // coalesced, no memset needed
}

// ---------------------------------------------------------------------------
// Pass 2: fold the 64 partials per class into one u64 hist (n lo32, g hi32).
// Wide grid so the 21.5 MB of partials stream at full BW.
// ---------------------------------------------------------------------------
__global__ void reduce_kernel(const unsigned* __restrict__ part,
                              unsigned long long* __restrict__ hist, int nb) {
    int idx = blockIdx.x * blockDim.x + threadIdx.x;   // c*nb + q
    if (idx >= C * nb) return;
    int c = idx / nb, q = idx - c * nb;
    const unsigned* basep = part + (size_t)c * NPART * nb + q;
    unsigned n = 0, g = 0;
#pragma unroll 8
    for (int p = 0; p < NPART; ++p) {
        unsigned v = basep[(size_t)p * nb];
        n += v & 0xffffu;
        g += v >> 16;
    }
    hist[idx] = (unsigned long long)n | ((unsigned long long)g << 32);
}

// ---------------------------------------------------------------------------
// Pass 3: per class, scan buckets in DESCENDING error order. Tied-bucket
// contribution telescopes to e_rep * (J(k+n,cg+g) - J(k,cg)),
// J(k,cg) = 1 - (G-cg)/(G+k-cg). Quantization error <= 0.5/nb per class.
// ---------------------------------------------------------------------------
__global__ __launch_bounds__(256) void scan_kernel(const unsigned long long* __restrict__ hist,
                                                   int nb,
                                                   double* __restrict__ loss_out,
                                                   unsigned long long* __restrict__ g_out) {
    int c = blockIdx.x;
    int tid = threadIdx.x;
    int per = nb / 256;

    __shared__ unsigned cn[NBMAX], cgx[NBMAX];
    for (int j = tid; j < nb; j += 256) {
        unsigned long long v = hist[(size_t)c * nb + j];
        cn[j] = (unsigned)(v & 0xffffffffULL);
        cgx[j] = (unsigned)(v >> 32);
    }
    __syncthreads();

    unsigned long long nsum = 0, gsum = 0;
    for (int j = 0; j < per; ++j) {
        int q = nb - 1 - (tid * per + j);
        nsum += cn[q]; gsum += cgx[q];
    }
    __shared__ unsigned long long sn[256], sg[256], exn[257], exg[257];
    sn[tid] = nsum; sg[tid] = gsum;
    __syncthreads();
    if (tid == 0) {
        unsigned long long an = 0, ag = 0;
        for (int i = 0; i < 256; ++i) { exn[i] = an; exg[i] = ag; an += sn[i]; ag += sg[i]; }
        exn[256] = an; exg[256] = ag;
    }
    __syncthreads();

    unsigned long long G = exg[256];
    double acc = 0.0;
    if (G > 0) {
        double Gd = (double)G;
        double k  = (double)exn[tid];
        double cg = (double)exg[tid];
        double jprev = 1.0 - (Gd - cg) / (Gd + k - cg);
        double inv_nb = 1.0 / (double)nb;
        for (int j = 0; j < per; ++j) {
            int q = nb - 1 - (tid * per + j);
            unsigned n = cn[q];
            if (n) {
                k += (double)n; cg += (double)cgx[q];
                double jnew = 1.0 - (Gd - cg) / (Gd + k - cg);
                acc += (((double)q + 0.5) * inv_nb) * (jnew - jprev);
                jprev = jnew;
            }
        }
    }
    __shared__ double red[256];
    red[tid] = acc;
    __syncthreads();
    for (int s = 128; s > 0; s >>= 1) {
        if (tid < s) red[tid] += red[tid + s];
        __syncthreads();
    }
    if (tid == 0) { loss_out[c] = red[0]; g_out[c] = G; }
}

// ---------------------------------------------------------------------------
// Pass 4: mean over present classes.
// ---------------------------------------------------------------------------
__global__ void finalize_kernel(const double* __restrict__ loss,
                                const unsigned long long* __restrict__ g,
                                float* __restrict__ out) {
    if (blockIdx.x == 0 && threadIdx.x == 0) {
        double s = 0.0; int np = 0;
        for (int c = 0; c < C; ++c) if (g[c] > 0) { s += loss[c]; ++np; }
        out[0] = (float)(s / (double)(np > 0 ? np : 1));
    }
}

extern "C" void kernel_launch(void* const* d_in, const int* in_sizes, int n_in,
                              void* d_out, int out_size, void* d_ws, size_t ws_size,
                              hipStream_t stream) {
    const float* pred = (const float*)d_in[0];
    float* out = (float*)d_out;

    // Bucket count: 4096 preferred (quantization <= 1.2e-4/class, threshold
    // 1.77e-2); shrink if workspace is tight.
    int nb = NBMAX;
    while (nb > 256) {
        size_t need = (size_t)N + (size_t)C * NPART * nb * 4 + (size_t)C * nb * 8 + 1024;
        if (need <= ws_size) break;
        nb >>= 1;
    }

    char* ws = (char*)d_ws;
    unsigned* lab = (unsigned*)ws;                                   // N bytes
    unsigned* part = (unsigned*)(ws + N);                            // C*NPART*nb*4
    unsigned long long* hist =
        (unsigned long long*)(ws + N + (size_t)C * NPART * nb * 4);  // C*nb*8
    double* loss = (double*)((char*)hist + (size_t)C * nb * 8);      // C*8
    unsigned long long* g = (unsigned long long*)(loss + C);         // C*8

    if (in_sizes[1] == N) {
        labels8_i32_kernel<<<dim3((N / 4 + 255) / 256), dim3(256), 0, stream>>>(
            (const int4*)d_in[1], lab);
    } else {
        labels8_i64_kernel<<<dim3((N / 4 + 255) / 256), dim3(256), 0, stream>>>(
            (const long long*)d_in[1], lab);
    }

    hist_kernel<<<dim3(CHUNKS, B * C), dim3(256), 0, stream>>>(
        (const float4*)pred, lab, part, nb, (float)nb);
    reduce_kernel<<<dim3((C * nb + 255) / 256), dim3(256), 0, stream>>>(part, hist, nb);
    scan_kernel<<<dim3(C), dim3(256), 0, stream>>>(hist, nb, loss, g);
    finalize_kernel<<<1, 64, 0, stream>>>(loss, g, out);
}

// Round 4
// 51.632 us; speedup vs baseline: 38.0168x; 1.2478x over previous
//
#include <hip/hip_runtime.h>
#include <stdint.h>

static constexpr int B = 8, C = 21, H = 512, W = 512;
static constexpr int HW = H * W;          // 262144
static constexpr int N = B * HW;          // 2097152 pixels
static constexpr int CHUNKS = 8;          // chunks per (b,c) plane
static constexpr int PPC = HW / CHUNKS;   // 32768 pixels per workgroup (< 2^16: u16-pack safe)
static constexpr int ITER = PPC / 4 / 256;// 32 x (float4 + int4) loads per thread
static constexpr int NPART = B * CHUNKS;  // 64 partial hists per class
static constexpr int NBMAX = 1024;        // quantization bound 0.5/nb = 4.9e-4 << 1.77e-2

// ---------------------------------------------------------------------------
// Pass 1: LDS-privatized per-(class,bucket) histogram. Packed u32: count in
// low 16, gt-count in high 16 (chunk = 32768 pixels -> no overflow). Labels
// (int32, validated in round 2) are read directly as int4; the 21x per-class
// re-read of the 8 MB label array is L2/L3-resident. Flush = plain coalesced
// stores to a per-workgroup slab: zero global atomics.
// ---------------------------------------------------------------------------
__global__ __launch_bounds__(256) void hist_kernel(const float4* __restrict__ pred,
                                                   const int4* __restrict__ lab4,
                                                   unsigned* __restrict__ part,
                                                   int nb, float nbf) {
    int chunk = blockIdx.x;               // 0..CHUNKS-1
    int bc = blockIdx.y;                  // b*C + c
    int b = bc / C, c = bc % C;
    int tid = threadIdx.x;

    __shared__ unsigned hcnt[NBMAX];
    for (int j = tid; j < nb; j += 256) hcnt[j] = 0;
    __syncthreads();

    const float4* pp = pred + ((size_t)bc * HW + (size_t)chunk * PPC) / 4;
    const int4* lp = lab4 + ((size_t)b * HW + (size_t)chunk * PPC) / 4;
#pragma unroll 4
    for (int i = 0; i < ITER; ++i) {
        int idx = i * 256 + tid;
        float4 p = pp[idx];
        int4 lv = lp[idx];
        float pe[4] = {p.x, p.y, p.z, p.w};
        int le[4] = {lv.x, lv.y, lv.z, lv.w};
#pragma unroll
        for (int j = 0; j < 4; ++j) {
            unsigned ismatch = (le[j] == c) ? 1u : 0u;
            float e = fabsf((float)ismatch - pe[j]);
            int q = (int)(e * nbf);
            q = q > nb - 1 ? nb - 1 : (q < 0 ? 0 : q);
            atomicAdd(&hcnt[q], 1u | (ismatch << 16));
        }
    }
    __syncthreads();

    unsigned* dst = part + ((size_t)c * NPART + (size_t)(b * CHUNKS + chunk)) * nb;
    for (int j = tid; j < nb; j += 256) dst[j] = hcnt[j];   // coalesced
}

// ---------------------------------------------------------------------------
// Pass 2: fold the 64 partials per class into one u64 hist (n lo32, g hi32).
// Wide grid streams the 5.4 MB slab. Also zeroes the scan's done-counter.
// ---------------------------------------------------------------------------
__global__ void reduce_kernel(const unsigned* __restrict__ part,
                              unsigned long long* __restrict__ hist, int nb,
                              unsigned* __restrict__ done) {
    if (blockIdx.x == 0 && threadIdx.x == 0) *done = 0u;
    int idx = blockIdx.x * blockDim.x + threadIdx.x;   // c*nb + q
    if (idx >= C * nb) return;
    int c = idx / nb, q = idx - c * nb;
    const unsigned* basep = part + (size_t)c * NPART * nb + q;
    unsigned n = 0, g = 0;
#pragma unroll 8
    for (int p = 0; p < NPART; ++p) {
        unsigned v = basep[(size_t)p * nb];
        n += v & 0xffffu;
        g += v >> 16;
    }
    hist[idx] = (unsigned long long)n | ((unsigned long long)g << 32);
}

// ---------------------------------------------------------------------------
// Pass 3: per class, scan buckets in DESCENDING error order. Tied-bucket
// contribution telescopes to e_rep * (J(k+n,cg+g) - J(k,cg)),
// J(k,cg) = 1 - (G-cg)/(G+k-cg). Last block to finish computes the mean over
// present classes (device-scope atomic + fences: order-independent sum).
// ---------------------------------------------------------------------------
__global__ __launch_bounds__(256) void scan_kernel(const unsigned long long* __restrict__ hist,
                                                   int nb,
                                                   double* __restrict__ loss_out,
                                                   unsigned long long* __restrict__ g_out,
                                                   unsigned* __restrict__ done,
                                                   float* __restrict__ out) {
    int c = blockIdx.x;
    int tid = threadIdx.x;
    int per = nb / 256;

    __shared__ unsigned cn[NBMAX], cgx[NBMAX];
    for (int j = tid; j < nb; j += 256) {
        unsigned long long v = hist[(size_t)c * nb + j];
        cn[j] = (unsigned)(v & 0xffffffffULL);
        cgx[j] = (unsigned)(v >> 32);
    }
    __syncthreads();

    unsigned long long nsum = 0, gsum = 0;
    for (int j = 0; j < per; ++j) {
        int q = nb - 1 - (tid * per + j);
        nsum += cn[q]; gsum += cgx[q];
    }
    __shared__ unsigned long long sn[256], sg[256], exn[257], exg[257];
    sn[tid] = nsum; sg[tid] = gsum;
    __syncthreads();
    if (tid == 0) {
        unsigned long long an = 0, ag = 0;
        for (int i = 0; i < 256; ++i) { exn[i] = an; exg[i] = ag; an += sn[i]; ag += sg[i]; }
        exn[256] = an; exg[256] = ag;
    }
    __syncthreads();

    unsigned long long G = exg[256];
    double acc = 0.0;
    if (G > 0) {
        double Gd = (double)G;
        double k  = (double)exn[tid];
        double cg = (double)exg[tid];
        double jprev = 1.0 - (Gd - cg) / (Gd + k - cg);
        double inv_nb = 1.0 / (double)nb;
        for (int j = 0; j < per; ++j) {
            int q = nb - 1 - (tid * per + j);
            unsigned n = cn[q];
            if (n) {
                k += (double)n; cg += (double)cgx[q];
                double jnew = 1.0 - (Gd - cg) / (Gd + k - cg);
                acc += (((double)q + 0.5) * inv_nb) * (jnew - jprev);
                jprev = jnew;
            }
        }
    }
    __shared__ double red[256];
    red[tid] = acc;
    __syncthreads();
    for (int s = 128; s > 0; s >>= 1) {
        if (tid < s) red[tid] += red[tid + s];
        __syncthreads();
    }
    if (tid == 0) {
        loss_out[c] = red[0];
        g_out[c] = G;
        __threadfence();                       // publish before signaling
        unsigned old = atomicAdd(done, 1u);    // device-scope
        if (old == C - 1) {                    // last block finalizes
            __threadfence();                   // acquire others' writes
            double s = 0.0; int np = 0;
            for (int i = 0; i < C; ++i)
                if (g_out[i] > 0) { s += loss_out[i]; ++np; }
            out[0] = (float)(s / (double)(np > 0 ? np : 1));
        }
    }
}

extern "C" void kernel_launch(void* const* d_in, const int* in_sizes, int n_in,
                              void* d_out, int out_size, void* d_ws, size_t ws_size,
                              hipStream_t stream) {
    const float* pred = (const float*)d_in[0];
    const int* tgt = (const int*)d_in[1];   // int64 narrowed to int32 by harness (validated round 2)
    float* out = (float*)d_out;

    int nb = NBMAX;
    while (nb > 256) {
        size_t need = (size_t)C * NPART * nb * 4 + (size_t)C * nb * 8 + 4096;
        if (need <= ws_size) break;
        nb >>= 1;
    }

    char* ws = (char*)d_ws;
    unsigned* part = (unsigned*)ws;                                  // C*NPART*nb*4
    unsigned long long* hist =
        (unsigned long long*)(ws + (size_t)C * NPART * nb * 4);      // C*nb*8
    double* loss = (double*)((char*)hist + (size_t)C * nb * 8);      // C*8
    unsigned long long* g = (unsigned long long*)(loss + C);         // C*8
    unsigned* done = (unsigned*)(g + C);                             // 4

    hist_kernel<<<dim3(CHUNKS, B * C), dim3(256), 0, stream>>>(
        (const float4*)pred, (const int4*)tgt, part, nb, (float)nb);
    reduce_kernel<<<dim3((C * nb + 255) / 256), dim3(256), 0, stream>>>(part, hist, nb, done);
    scan_kernel<<<dim3(C), dim3(256), 0, stream>>>(hist, nb, loss, g, done, out);
}